// Round 3
// baseline (155.355 us; speedup 1.0000x reference)
//
#include <hip/hip_runtime.h>

// RT-DETR Hungarian matcher cost matrix.
// B=32, Q=300, C=80, T=100. Out: (B*Q) x (B*T) = 9600 x 3200 fp32 = 122.9 MB.
// cost = 5*L1 + 2*focal_class - 2*GIoU
//
// R6 = R5 resubmitted verbatim (R5 bench died to infra: container failed
//   twice; no kernel-side evidence of a problem).
// R4/R5 theory (still untested): kernel is stall-bound, not issue-bound
//   (~72us on-device vs ~25us overlapped-work estimate; harness dur_us also
//   contains a ~77us poison fill we cannot touch).
//   - 8 x (4-row unrolled) row loop: full 32-row unroll was ~40KB > 32KB I$.
//   - __launch_bounds__(256,4): 16 waves/CU for latency hiding.
//   - non-temporal stores: 123MB write-once stream keeps L2 for inputs.
//   - __expf/__logf in fill phase (tolerance headroom).

constexpr int BB = 32, QQ = 300, CN = 80, TT = 100;
constexpr int NQ = BB * QQ;       // 9600 query rows
constexpr int NT = BB * TT;       // 3200 targets
constexpr int JG = NT / 4;        // 800 groups of 4 targets
constexpr int RCHUNK = 32;        // query rows per block (9600 = 300 * 32)
constexpr int STRIPES = (JG + 255) / 256;   // 4 column stripes
constexpr int CCN = RCHUNK * CN;  // 2560 class-cost entries per block

typedef float vfloat4 __attribute__((ext_vector_type(4)));

__global__ __launch_bounds__(256, 4) void fused_kernel(
    const float*  __restrict__ logits,        // NQ*80
    const float4* __restrict__ pred_boxes,    // NQ   (cx,cy,w,h)
    const int*    __restrict__ labels,        // NT
    const float4* __restrict__ target_boxes,  // NT   (cx,cy,w,h)
    float4*       __restrict__ out)           // NQ * JG
{
  const int tid  = threadIdx.x;
  const int jg   = blockIdx.x * 256 + tid;    // target group [0, 800)
  const int row0 = blockIdx.y * RCHUNK;

  __shared__ float  s_cc[CCN];                // [32 rows][80 classes], 10 KB
  __shared__ float4 s_pred[RCHUNK];

  // ---- fill phase: focal class cost (+2 giou-constant bias) ----
  const float* lgbase = logits + (size_t)row0 * CN;
#pragma unroll
  for (int i = 0; i < CCN / 256; ++i) {
    const int e = i * 256 + tid;
    float x = lgbase[e];
    float p = 1.0f / (1.0f + __expf(-x));
    float omp = 1.0f - p;
    float neg = 0.75f * p * p * (-__logf(omp + 1e-8f));
    float pos = 0.25f * omp * omp * (-__logf(p + 1e-8f));
    s_cc[e] = 2.0f * (pos - neg) + 2.0f;      // C_CLASS=2 pre-scaled, +2 bias
  }
  if (tid < RCHUNK) s_pred[tid] = pred_boxes[row0 + tid];
  __syncthreads();
  if (jg >= JG) return;

  // ---- per-thread target state: 4 targets, pinned in registers ----
  float tcx[4], tcy[4], tw[4], th[4];
  float tx0[4], ty0[4], tx1[4], ty1[4], ta[4];
  const float* ccbase[4];                     // s_cc + label; row via r*CN
#pragma unroll
  for (int k = 0; k < 4; ++k) {
    float4 t = target_boxes[jg * 4 + k];
    tcx[k] = t.x; tcy[k] = t.y; tw[k] = t.z; th[k] = t.w;
    tx0[k] = t.x - 0.5f * t.z;  ty0[k] = t.y - 0.5f * t.w;
    tx1[k] = t.x + 0.5f * t.z;  ty1[k] = t.y + 0.5f * t.w;
    ta[k]  = t.z * t.w;
    ccbase[k] = s_cc + labels[jg * 4 + k];
  }

  vfloat4* outp = reinterpret_cast<vfloat4*>(out + (size_t)row0 * JG + jg);

  // 8 iterations x 4-row unrolled window: ~4.5KB hot loop (fits I$),
  // imm-offset ds_reads within the window, strength-reduced bases across it.
  for (int rb = 0; rb < RCHUNK; rb += 4) {
#pragma unroll
    for (int ri = 0; ri < 4; ++ri) {
      const int r = rb + ri;
      float4 p = s_pred[r];                    // ds_read_b128
      float px0 = p.x - 0.5f * p.z, py0 = p.y - 0.5f * p.w;
      float px1 = p.x + 0.5f * p.z, py1 = p.y + 0.5f * p.w;
      float pa  = p.z * p.w;

      float res[4];
#pragma unroll
      for (int k = 0; k < 4; ++k) {
        // L1 in center format
        float l1 = fabsf(p.x - tcx[k]) + fabsf(p.y - tcy[k]) +
                   fabsf(p.z - tw[k])  + fabsf(p.w - th[k]);
        // intersection
        float ltx = fmaxf(px0, tx0[k]), lty = fmaxf(py0, ty0[k]);
        float rbx = fminf(px1, tx1[k]), rby = fminf(py1, ty1[k]);
        float iw = fmaxf(rbx - ltx, 0.0f), ih = fmaxf(rby - lty, 0.0f);
        float inter = iw * ih;
        float uni = pa + ta[k] - inter;
        // enclosing box (max-min >= 0 here, no clamp needed)
        float ex0 = fminf(px0, tx0[k]), ey0 = fminf(py0, ty0[k]);
        float ex1 = fmaxf(px1, tx1[k]), ey1 = fmaxf(py1, ty1[k]);
        float enc = (ex1 - ex0) * (ey1 - ey0);
        // -2*giou = 2 - 2*iou - 2*uni/enc; +2 lives in the class table
        float iou = inter * __builtin_amdgcn_rcpf(uni);
        float une = uni   * __builtin_amdgcn_rcpf(enc);
        float cls = ccbase[k][r * CN];         // ds_read_b32 gather
        float acc = fmaf(5.0f, l1, cls);
        acc       = fmaf(-2.0f, iou, acc);
        res[k]    = fmaf(-2.0f, une, acc);
      }
      vfloat4 v = { res[0], res[1], res[2], res[3] };
      __builtin_nontemporal_store(v, &outp[(size_t)r * JG]);
    }
  }
}

extern "C" void kernel_launch(void* const* d_in, const int* in_sizes, int n_in,
                              void* d_out, int out_size, void* d_ws, size_t ws_size,
                              hipStream_t stream) {
  const float*  logits = (const float*)d_in[0];
  const float4* pred   = (const float4*)d_in[1];
  const int*    labels = (const int*)d_in[2];
  const float4* tboxes = (const float4*)d_in[3];
  float4* out = (float4*)d_out;

  dim3 grid(STRIPES, NQ / RCHUNK);             // (4, 300) = 1200 blocks
  fused_kernel<<<grid, 256, 0, stream>>>(logits, pred, labels, tboxes, out);
}

// Round 4
// 154.225 us; speedup vs baseline: 1.0073x; 1.0073x over previous
//
#include <hip/hip_runtime.h>

// RT-DETR Hungarian matcher cost matrix.
// B=32, Q=300, C=80, T=100. Out: (B*Q) x (B*T) = 9600 x 3200 fp32 = 122.9 MB.
// cost = 5*L1 + 2*focal_class - 2*GIoU
//
// R7 — discriminating experiment between two readings of the flat timing:
//   (b) kernel ~74us, wall = VALU<->LDS interleave stalls (cls gather is 16
//       scattered ds_read_b32 per 4-row window, ~85% concurrent LDS demand)
//   (i) kernel ~20-40us already; dur_us dominated by poison fill (77us) +
//       ~97 tiny restore dispatches per iteration (Dispatch_Id gap = 98).
//   This version attacks (b): class-cost LUT transposed to [class][row],
//   stride 36 floats (144B: 16B-aligned for ds_read_b128, banks spread by
//   4*label) -> per window each target's cls is ONE b128 hoisted out of the
//   inner loop (16 b32 -> 4 b128). Single-rcp GIoU: one v_rcp instead of two.
//   If dur_us stays ~154 again, reading (i) is confirmed -> roofline.
// Kept from R6: 8x(4-row) window loop, __launch_bounds__(256,4), NT stores,
//   __expf/__logf fill phase, +2 giou bias folded into the class table.

constexpr int BB = 32, QQ = 300, CN = 80, TT = 100;
constexpr int NQ = BB * QQ;       // 9600 query rows
constexpr int NT = BB * TT;       // 3200 targets
constexpr int JG = NT / 4;        // 800 groups of 4 targets
constexpr int RCHUNK = 32;        // query rows per block (9600 = 300 * 32)
constexpr int STRIPES = (JG + 255) / 256;   // 4 column stripes
constexpr int CCN = RCHUNK * CN;  // 2560 class-cost entries per block
constexpr int CS = 36;            // transposed-LUT row stride (floats):
                                  // 144B = 16B-aligned b128 for every class,
                                  // bank start = (4*label + rb) % 32

typedef float vfloat4 __attribute__((ext_vector_type(4)));

__global__ __launch_bounds__(256, 4) void fused_kernel(
    const float*  __restrict__ logits,        // NQ*80
    const float4* __restrict__ pred_boxes,    // NQ   (cx,cy,w,h)
    const int*    __restrict__ labels,        // NT
    const float4* __restrict__ target_boxes,  // NT   (cx,cy,w,h)
    float4*       __restrict__ out)           // NQ * JG
{
  const int tid  = threadIdx.x;
  const int jg   = blockIdx.x * 256 + tid;    // target group [0, 800)
  const int row0 = blockIdx.y * RCHUNK;

  __shared__ float  s_ccT[CN * CS];           // [80 classes][32 rows+pad], 11.5 KB
  __shared__ float4 s_pred[RCHUNK];

  // ---- fill phase: focal class cost (+2 giou-constant bias), transposed ----
  const float* lgbase = logits + (size_t)row0 * CN;
#pragma unroll
  for (int i = 0; i < CCN / 256; ++i) {
    const int e = i * 256 + tid;
    const int r = e / CN, c = e - r * CN;     // magic-mul div by 80
    float x = lgbase[e];                      // coalesced read
    float p = 1.0f / (1.0f + __expf(-x));
    float omp = 1.0f - p;
    float neg = 0.75f * p * p * (-__logf(omp + 1e-8f));
    float pos = 0.25f * omp * omp * (-__logf(p + 1e-8f));
    s_ccT[c * CS + r] = 2.0f * (pos - neg) + 2.0f;  // C_CLASS=2 + 2 bias
  }
  if (tid < RCHUNK) s_pred[tid] = pred_boxes[row0 + tid];
  __syncthreads();
  if (jg >= JG) return;

  // ---- per-thread target state: 4 targets, pinned in registers ----
  float tcx[4], tcy[4], tw[4], th[4];
  float tx0[4], ty0[4], tx1[4], ty1[4], ta[4];
  const float* ccT[4];                        // &s_ccT[label*CS]
#pragma unroll
  for (int k = 0; k < 4; ++k) {
    float4 t = target_boxes[jg * 4 + k];
    tcx[k] = t.x; tcy[k] = t.y; tw[k] = t.z; th[k] = t.w;
    tx0[k] = t.x - 0.5f * t.z;  ty0[k] = t.y - 0.5f * t.w;
    tx1[k] = t.x + 0.5f * t.z;  ty1[k] = t.y + 0.5f * t.w;
    ta[k]  = t.z * t.w;
    ccT[k] = s_ccT + labels[jg * 4 + k] * CS;
  }

  vfloat4* outp = reinterpret_cast<vfloat4*>(out + (size_t)row0 * JG + jg);

  for (int rb = 0; rb < RCHUNK; rb += 4) {
    // one ds_read_b128 per target = this window's 4 rows of class cost
    vfloat4 cls4[4];
#pragma unroll
    for (int k = 0; k < 4; ++k)
      cls4[k] = *reinterpret_cast<const vfloat4*>(ccT[k] + rb);

#pragma unroll
    for (int ri = 0; ri < 4; ++ri) {
      float4 p = s_pred[rb + ri];              // broadcast ds_read_b128
      float px0 = p.x - 0.5f * p.z, py0 = p.y - 0.5f * p.w;
      float px1 = p.x + 0.5f * p.z, py1 = p.y + 0.5f * p.w;
      float pa  = p.z * p.w;

      float res[4];
#pragma unroll
      for (int k = 0; k < 4; ++k) {
        // L1 in center format
        float l1 = fabsf(p.x - tcx[k]) + fabsf(p.y - tcy[k]) +
                   fabsf(p.z - tw[k])  + fabsf(p.w - th[k]);
        // intersection
        float ltx = fmaxf(px0, tx0[k]), lty = fmaxf(py0, ty0[k]);
        float rbx = fminf(px1, tx1[k]), rby = fminf(py1, ty1[k]);
        float iw = fmaxf(rbx - ltx, 0.0f), ih = fmaxf(rby - lty, 0.0f);
        float inter = iw * ih;
        float uni = pa + ta[k] - inter;
        // enclosing box (max-min >= 0 here, no clamp needed)
        float ex0 = fminf(px0, tx0[k]), ey0 = fminf(py0, ty0[k]);
        float ex1 = fmaxf(px1, tx1[k]), ey1 = fmaxf(py1, ty1[k]);
        float enc = (ex1 - ex0) * (ey1 - ey0);
        // -2*giou + 2 = 2 - 2*(iou + uni/enc)
        //             = 2 - 2*(inter*enc + uni^2) / (uni*enc); +2 in table
        float num = fmaf(uni, uni, inter * enc);
        float den = uni * enc;
        float ratio = num * __builtin_amdgcn_rcpf(den);
        float acc = fmaf(5.0f, l1, cls4[k][ri]);
        res[k]    = fmaf(-2.0f, ratio, acc);
      }
      vfloat4 v = { res[0], res[1], res[2], res[3] };
      __builtin_nontemporal_store(v, &outp[(size_t)(rb + ri) * JG]);
    }
  }
}

extern "C" void kernel_launch(void* const* d_in, const int* in_sizes, int n_in,
                              void* d_out, int out_size, void* d_ws, size_t ws_size,
                              hipStream_t stream) {
  const float*  logits = (const float*)d_in[0];
  const float4* pred   = (const float4*)d_in[1];
  const int*    labels = (const int*)d_in[2];
  const float4* tboxes = (const float4*)d_in[3];
  float4* out = (float4*)d_out;

  dim3 grid(STRIPES, NQ / RCHUNK);             // (4, 300) = 1200 blocks
  fused_kernel<<<grid, 256, 0, stream>>>(logits, pred, labels, tboxes, out);
}